// Round 3
// baseline (2924.311 us; speedup 1.0000x reference)
//
#include <hip/hip_runtime.h>
#include <math.h>

// Problem constants (MSDeformMatchV2HeaderAttn)
#define BB 2
#define LQ 1024
#define DM 256
#define NH 8
#define DH 32
#define NL 4
#define HWsp 1024   // 32*32
#define LIN 4096
#define K9 36

// ---------------------------------------------------------------------------
// Kernel 1 (v2): fused corr + stable top-4, no corr materialization.
// corr[q][k] = dot(Q[q], V[k]) over d=32, fp32, ascending-d association.
// Stable top-4 == top-4 under (value desc, index asc): distribute as
// per-thread ascending-k INSERT4 + lexicographic butterfly merge over tk.
// Grid: (16 q-chunks of 64, 4 levels, 16 n*h) x 256 threads.
// Thread (tq=tid>>4, tk=tid&15): tile = 4 q-rows x 8 k-cols per 128-k chunk.
// ---------------------------------------------------------------------------
#define INSERT4Q(qi, val, index)                                              \
  {                                                                           \
    const float v_ = (val);                                                   \
    const int ix_ = (index);                                                  \
    if (v_ > v3[qi]) {                                                        \
      if (v_ > v1[qi]) {                                                      \
        if (v_ > v0[qi]) {                                                    \
          v3[qi] = v2[qi]; i3[qi] = i2[qi]; v2[qi] = v1[qi]; i2[qi] = i1[qi]; \
          v1[qi] = v0[qi]; i1[qi] = i0[qi]; v0[qi] = v_; i0[qi] = ix_;        \
        } else {                                                              \
          v3[qi] = v2[qi]; i3[qi] = i2[qi]; v2[qi] = v1[qi]; i2[qi] = i1[qi]; \
          v1[qi] = v_; i1[qi] = ix_;                                          \
        }                                                                     \
      } else {                                                                \
        if (v_ > v2[qi]) {                                                    \
          v3[qi] = v2[qi]; i3[qi] = i2[qi]; v2[qi] = v_; i2[qi] = ix_;        \
        } else {                                                              \
          v3[qi] = v_; i3[qi] = ix_;                                          \
        }                                                                     \
      }                                                                       \
    }                                                                         \
  }

// a := lexmax(a, b)  under (value desc, index asc)
#define LMAX(av, ai, bv, bi)                                   \
  {                                                            \
    const bool g_ = ((av) > (bv)) || ((av) == (bv) && (ai) < (bi)); \
    if (!g_) { (av) = (bv); (ai) = (bi); }                     \
  }
// compare-exchange: order (a,b) so a >=lex b
#define CEX(av, ai, bv, bi)                                    \
  {                                                            \
    const bool g_ = ((av) > (bv)) || ((av) == (bv) && (ai) < (bi)); \
    const float tv_ = g_ ? (av) : (bv);                        \
    const int ti_ = g_ ? (ai) : (bi);                          \
    (bv) = g_ ? (bv) : (av); (bi) = g_ ? (bi) : (ai);          \
    (av) = tv_; (ai) = ti_;                                    \
  }

__global__ __launch_bounds__(256, 4) void corr_topk_kernel(
    const float* __restrict__ query, const float* __restrict__ value,
    int* __restrict__ idx_out) {
  __shared__ float qR[64][36];   // [q_local][d], row-major, pad->36
  __shared__ float vR[128][36];  // [k_local][d], d4-columns XOR-swizzled by (k>>3)&7

  const int tid = threadIdx.x;
  const int nh = blockIdx.z;  // n*8+h
  const int n = nh >> 3, h = nh & 7;
  const int l = blockIdx.y;
  const int qb = blockIdx.x << 6;  // 64 queries per block
  const int tq = tid >> 4, tk = tid & 15;
  const int d4s = tid & 7, r0 = tid >> 3;  // staging mapping

  // Stage qR (row-major copy, coalesced float4)
  {
    const float* qg = query + (size_t)(n * LQ + qb) * DM + h * DH;
    #pragma unroll
    for (int p = 0; p < 2; ++p) {
      const int r = r0 + p * 32;
      *(float4*)&qR[r][d4s * 4] = *(const float4*)(qg + (size_t)r * DM + d4s * 4);
    }
  }

  // per-thread top-4 state for 4 q-rows
  float v0[4], v1[4], v2[4], v3[4];
  int i0[4], i1[4], i2[4], i3[4];
  #pragma unroll
  for (int qi = 0; qi < 4; ++qi) {
    v0[qi] = v1[qi] = v2[qi] = v3[qi] = -INFINITY;
    i0[qi] = i1[qi] = i2[qi] = i3[qi] = 0;
  }

  const float* vgbase = value + (size_t)(n * LIN + l * HWsp) * DM + h * DH;

  for (int it = 0; it < 8; ++it) {
    // Stage vR chunk: 128 rows x 32 d, float4, column-swizzled
    #pragma unroll
    for (int p = 0; p < 4; ++p) {
      const int kr = r0 + p * 32;
      const float4 t = *(const float4*)(vgbase + (size_t)(it * 128 + kr) * DM + d4s * 4);
      *(float4*)&vR[kr][4 * (d4s ^ ((kr >> 3) & 7))] = t;
    }
    __syncthreads();

    float acc[4][8];
    #pragma unroll
    for (int qi = 0; qi < 4; ++qi)
      #pragma unroll
      for (int kj = 0; kj < 8; ++kj) acc[qi][kj] = 0.f;

    #pragma unroll
    for (int d4 = 0; d4 < 8; ++d4) {
      float4 qv[4];
      #pragma unroll
      for (int qi = 0; qi < 4; ++qi)
        qv[qi] = *(const float4*)&qR[tq * 4 + qi][d4 * 4];
      #pragma unroll
      for (int kj = 0; kj < 8; ++kj) {
        const int kloc = tk * 8 + kj;
        const float4 vv = *(const float4*)&vR[kloc][4 * (d4 ^ (tk & 7))];
        #pragma unroll
        for (int qi = 0; qi < 4; ++qi) {
          float s = acc[qi][kj];
          s = fmaf(qv[qi].x, vv.x, s);
          s = fmaf(qv[qi].y, vv.y, s);
          s = fmaf(qv[qi].z, vv.z, s);
          s = fmaf(qv[qi].w, vv.w, s);
          acc[qi][kj] = s;
        }
      }
    }

    // local stable top-4 update (ascending k within thread)
    #pragma unroll
    for (int qi = 0; qi < 4; ++qi) {
      #pragma unroll
      for (int kj = 0; kj < 8; ++kj) {
        INSERT4Q(qi, acc[qi][kj], it * 128 + tk * 8 + kj);
      }
    }
    __syncthreads();
  }

  // Butterfly lexicographic merge across the 16 tk-threads (within quarter-wave)
  #pragma unroll
  for (int m = 1; m < 16; m <<= 1) {
    #pragma unroll
    for (int qi = 0; qi < 4; ++qi) {
      const float b0 = __shfl_xor(v0[qi], m);
      const float b1 = __shfl_xor(v1[qi], m);
      const float b2 = __shfl_xor(v2[qi], m);
      const float b3 = __shfl_xor(v3[qi], m);
      const int j0 = __shfl_xor(i0[qi], m);
      const int j1 = __shfl_xor(i1[qi], m);
      const int j2 = __shfl_xor(i2[qi], m);
      const int j3 = __shfl_xor(i3[qi], m);
      // L_i = lexmax(a_i, b_{3-i}) -> bitonic, contains union top-4
      LMAX(v0[qi], i0[qi], b3, j3);
      LMAX(v1[qi], i1[qi], b2, j2);
      LMAX(v2[qi], i2[qi], b1, j1);
      LMAX(v3[qi], i3[qi], b0, j0);
      // bitonic sort4 desc
      CEX(v0[qi], i0[qi], v2[qi], i2[qi]);
      CEX(v1[qi], i1[qi], v3[qi], i3[qi]);
      CEX(v0[qi], i0[qi], v1[qi], i1[qi]);
      CEX(v2[qi], i2[qi], v3[qi], i3[qi]);
    }
  }

  if (tk == 0) {
    #pragma unroll
    for (int qi = 0; qi < 4; ++qi) {
      const int q = qb + tq * 4 + qi;
      // idx_buf layout: [n][h][l][q][4] int32
      ((int4*)idx_out)[(((size_t)nh * NL + l) << 10) + q] =
          make_int4(i0[qi], i1[qi], i2[qi], i3[qi]);
    }
  }
}

// ---------------------------------------------------------------------------
// Kernel 2: loc output. res=clip(idx+delta,0,961); loc=(res>>5, res&31)/32.
// One thread per (n,q,h,l,k9) pair -> writes float2. Exact in fp32.
// ---------------------------------------------------------------------------
__global__ __launch_bounds__(256) void loc_kernel(const int* __restrict__ idx_buf,
                                                  float* __restrict__ loc) {
  const int t = blockIdx.x * 256 + threadIdx.x;  // < 2359296
  const int k = t % 36;
  int rest = t / 36;
  const int l = rest & 3; rest >>= 2;
  const int h = rest & 7; rest >>= 3;
  const int q = rest & 1023;
  const int n = rest >> 10;
  const int p = k & 3, dd = k >> 2;  // delta-major: k = dd*4 + p
  const int idx = idx_buf[(((((n << 3) + h) * NL + l) << 10) + q) * 4 + p];
  const int delta = ((dd / 3) - 1) * 32 + (dd % 3) - 1;  // {-33,-32,-31,-1,0,1,31,32,33}
  int res = idx + delta;
  res = min(max(res, 0), 961);
  const int W = res >> 5, H = res & 31;
  ((float2*)loc)[t] = make_float2((float)W * 0.03125f, (float)H * 0.03125f);
}

// ---------------------------------------------------------------------------
// Kernel 3: gather+average. All bilinear weights are exactly 0.25; corners of
// cell (H=res&31, W=res>>5) are rows {g, g-1, g-32, g-33}, g = H*32+W, gated
// by W>=1 / H>=1 (gates applied as 0/1 weights, addresses clamped to >=0 so
// loads are unconditional and exec-full -> no divergence).
// Block = (n,q); thread = (l, h, d4): wave = one level; float4 per lane ->
// 1 KiB per load instruction; 144 independent loads per thread.
// LDS reduction over the 4 levels at the end. acc = (1/576) * sum.
// ---------------------------------------------------------------------------
__global__ __launch_bounds__(256) void gather_kernel(
    const float* __restrict__ value, const int* __restrict__ idx_buf,
    float* __restrict__ acc_out) {
  __shared__ float red[NL][DM];
  const int nq = blockIdx.x;  // n*1024+q
  const int n = nq >> 10, q = nq & 1023;
  const int tid = threadIdx.x;
  const int l = tid >> 6;          // wave index = level
  const int h = (tid >> 3) & 7;
  const int d4 = tid & 7;          // float4 lane within the 32-float head dim

  const int4 id4 =
      ((const int4*)idx_buf)[((((size_t)((n << 3) + h)) * NL + l) << 10) + q];

  // base: value[n][l*1024 + row][h*32 + d4*4 ..], row stride = 64 float4
  const float4* vb4 =
      (const float4*)(value + (size_t)(n * LIN + l * HWsp) * DM + h * DH) + d4;

  float4 a = make_float4(0.f, 0.f, 0.f, 0.f);
  #pragma unroll
  for (int p = 0; p < 4; ++p) {
    const int idx = (p == 0) ? id4.x : (p == 1) ? id4.y : (p == 2) ? id4.z : id4.w;
    #pragma unroll
    for (int dy = -1; dy <= 1; ++dy) {
      #pragma unroll
      for (int dx = -1; dx <= 1; ++dx) {
        int res = idx + dy * 32 + dx;
        res = min(max(res, 0), 961);
        const int W = res >> 5, H = res & 31;
        const int g = (H << 5) + W;
        const float wW = (W >= 1) ? 1.f : 0.f;
        const float wH = (H >= 1) ? 1.f : 0.f;
        const float wB = wW * wH;
        const float4 c0 = vb4[(size_t)g * 64];
        const float4 c1 = vb4[(size_t)max(g - 1, 0) * 64];
        const float4 c2 = vb4[(size_t)max(g - 32, 0) * 64];
        const float4 c3 = vb4[(size_t)max(g - 33, 0) * 64];
        a.x += c0.x + wW * c1.x + wH * c2.x + wB * c3.x;
        a.y += c0.y + wW * c1.y + wH * c2.y + wB * c3.y;
        a.z += c0.z + wW * c1.z + wH * c2.z + wB * c3.z;
        a.w += c0.w + wW * c1.w + wH * c2.w + wB * c3.w;
      }
    }
  }

  const int col = h * DH + d4 * 4;
  red[l][col + 0] = a.x;
  red[l][col + 1] = a.y;
  red[l][col + 2] = a.z;
  red[l][col + 3] = a.w;
  __syncthreads();
  const float s = red[0][tid] + red[1][tid] + red[2][tid] + red[3][tid];
  acc_out[(size_t)nq * DM + tid] = s * (1.0f / 576.0f);
}

// ---------------------------------------------------------------------------
// Kernel 4: out = acc @ W^T + b.  256 blocks x 256 threads, 8 q-rows/block.
// ---------------------------------------------------------------------------
__global__ __launch_bounds__(256) void proj_kernel(
    const float* __restrict__ acc_in, const float* __restrict__ W,
    const float* __restrict__ bias, float* __restrict__ out) {
  __shared__ float la[8][256];
  const int qb = blockIdx.x << 3;
  const int tid = threadIdx.x;
  for (int i = tid; i < 8 * 256; i += 256)
    la[i >> 8][i & 255] = acc_in[((size_t)qb << 8) + i];
  __syncthreads();
  const float* wrow = W + (size_t)tid * 256;
  float s0 = 0.f, s1 = 0.f, s2 = 0.f, s3 = 0.f, s4 = 0.f, s5 = 0.f, s6 = 0.f, s7 = 0.f;
  for (int c0 = 0; c0 < 256; c0 += 4) {
    const float4 wv = *(const float4*)(wrow + c0);
    #define PROJ_STEP(qi, sreg)                                   \
      {                                                           \
        const float4 av = *(const float4*)&la[qi][c0];            \
        sreg = fmaf(wv.x, av.x, sreg);                            \
        sreg = fmaf(wv.y, av.y, sreg);                            \
        sreg = fmaf(wv.z, av.z, sreg);                            \
        sreg = fmaf(wv.w, av.w, sreg);                            \
      }
    PROJ_STEP(0, s0) PROJ_STEP(1, s1) PROJ_STEP(2, s2) PROJ_STEP(3, s3)
    PROJ_STEP(4, s4) PROJ_STEP(5, s5) PROJ_STEP(6, s6) PROJ_STEP(7, s7)
    #undef PROJ_STEP
  }
  const float bj = bias[tid];
  out[(size_t)(qb + 0) * 256 + tid] = s0 + bj;
  out[(size_t)(qb + 1) * 256 + tid] = s1 + bj;
  out[(size_t)(qb + 2) * 256 + tid] = s2 + bj;
  out[(size_t)(qb + 3) * 256 + tid] = s3 + bj;
  out[(size_t)(qb + 4) * 256 + tid] = s4 + bj;
  out[(size_t)(qb + 5) * 256 + tid] = s5 + bj;
  out[(size_t)(qb + 6) * 256 + tid] = s6 + bj;
  out[(size_t)(qb + 7) * 256 + tid] = s7 + bj;
}

// ---------------------------------------------------------------------------
extern "C" void kernel_launch(void* const* d_in, const int* in_sizes, int n_in,
                              void* d_out, int out_size, void* d_ws, size_t ws_size,
                              hipStream_t stream) {
  (void)in_sizes; (void)n_in; (void)out_size; (void)ws_size;
  const float* query = (const float*)d_in[0];
  // d_in[1] reference_points: unused by the reference math
  const float* value = (const float*)d_in[2];
  // d_in[3], d_in[4]: spatial shapes / level start (int64) -- constants here
  const float* opw = (const float*)d_in[5];
  const float* opb = (const float*)d_in[6];

  float* out = (float*)d_out;                       // [2,1024,256]
  float* loc = out + (size_t)BB * LQ * DM;          // [2,1024,8,4,36,2]

  int* idx_buf = (int*)d_ws;                                        // 1 MB
  float* acc_buf = (float*)((char*)d_ws + (size_t)BB * NH * NL * LQ * 4 * sizeof(int));

  corr_topk_kernel<<<dim3(16, NL, BB * NH), 256, 0, stream>>>(query, value, idx_buf);
  loc_kernel<<<dim3((BB * LQ * NH * NL * K9) / 256), 256, 0, stream>>>(idx_buf, loc);
  gather_kernel<<<dim3(BB * LQ), 256, 0, stream>>>(value, idx_buf, acc_buf);
  proj_kernel<<<dim3(BB * LQ / 8), 256, 0, stream>>>(acc_buf, opw, opb, out);
}

// Round 4
// 328.508 us; speedup vs baseline: 8.9018x; 8.9018x over previous
//
#include <hip/hip_runtime.h>
#include <math.h>

// Problem constants (MSDeformMatchV2HeaderAttn)
#define BB 2
#define LQ 1024
#define DM 256
#define NH 8
#define DH 32
#define NL 4
#define HWsp 1024   // 32*32
#define LIN 4096
#define K9 36

// ---------------------------------------------------------------------------
// Kernel 1 (v3): fused corr + stable top-4, no corr materialization, small
// per-thread state (R1's 4q x 4k matmul tile + R2's validated merge).
// corr[q][k] = dot(Q[q], V[k]) over d=32, fp32, ascending-d association.
// Stable top-4 == top-4 under (value desc, index asc): per-thread ascending-k
// INSERT4 on the thread's own 4 k-columns, then lexicographic butterfly
// merge across the 16 tk-threads.
// Grid: (16 q-chunks of 64, 4 levels, 16 n*h) x 256 threads.
// ---------------------------------------------------------------------------
#define INSERT4Q(qi, val, index)                                              \
  {                                                                           \
    const float v_ = (val);                                                   \
    const int ix_ = (index);                                                  \
    if (v_ > v3[qi]) {                                                        \
      if (v_ > v1[qi]) {                                                      \
        if (v_ > v0[qi]) {                                                    \
          v3[qi] = v2[qi]; i3[qi] = i2[qi]; v2[qi] = v1[qi]; i2[qi] = i1[qi]; \
          v1[qi] = v0[qi]; i1[qi] = i0[qi]; v0[qi] = v_; i0[qi] = ix_;        \
        } else {                                                              \
          v3[qi] = v2[qi]; i3[qi] = i2[qi]; v2[qi] = v1[qi]; i2[qi] = i1[qi]; \
          v1[qi] = v_; i1[qi] = ix_;                                          \
        }                                                                     \
      } else {                                                                \
        if (v_ > v2[qi]) {                                                    \
          v3[qi] = v2[qi]; i3[qi] = i2[qi]; v2[qi] = v_; i2[qi] = ix_;        \
        } else {                                                              \
          v3[qi] = v_; i3[qi] = ix_;                                          \
        }                                                                     \
      }                                                                       \
    }                                                                         \
  }

// a := lexmax(a, b)  under (value desc, index asc)
#define LMAX(av, ai, bv, bi)                                        \
  {                                                                 \
    const bool g_ = ((av) > (bv)) || ((av) == (bv) && (ai) < (bi)); \
    if (!g_) { (av) = (bv); (ai) = (bi); }                          \
  }
// compare-exchange: order (a,b) so a >=lex b
#define CEX(av, ai, bv, bi)                                         \
  {                                                                 \
    const bool g_ = ((av) > (bv)) || ((av) == (bv) && (ai) < (bi)); \
    const float tv_ = g_ ? (av) : (bv);                             \
    const int ti_ = g_ ? (ai) : (bi);                               \
    (bv) = g_ ? (bv) : (av); (bi) = g_ ? (bi) : (ai);               \
    (av) = tv_; (ai) = ti_;                                         \
  }

__global__ __launch_bounds__(256) void corr_topk_kernel(
    const float* __restrict__ query, const float* __restrict__ value,
    int* __restrict__ idx_out) {
  __shared__ float qT[32][68];  // [d][q_local], pad 68
  __shared__ float vT[32][68];  // [d][k_local]

  const int tid = threadIdx.x;
  const int nh = blockIdx.z;  // n*8+h
  const int n = nh >> 3, h = nh & 7;
  const int l = blockIdx.y;
  const int qb = blockIdx.x << 6;        // 64 queries per block
  const int d = tid & 31, r = tid >> 5;  // loader mapping
  const int tq = tid >> 4, tk = tid & 15;

  // Stage Q^T once: qT[d][q] = query[n][qb+q][h*32+d]
  {
    const float* qg = query + (size_t)(n * LQ + qb) * DM + h * DH + d;
    #pragma unroll
    for (int i = 0; i < 8; ++i) qT[d][r + (i << 3)] = qg[(size_t)(r + (i << 3)) * DM];
  }

  // per-thread top-4 state for 4 q-rows (sorted desc, lexicographic)
  float v0[4], v1[4], v2[4], v3[4];
  int i0[4], i1[4], i2[4], i3[4];
  #pragma unroll
  for (int qi = 0; qi < 4; ++qi) {
    v0[qi] = v1[qi] = v2[qi] = v3[qi] = -INFINITY;
    i0[qi] = i1[qi] = i2[qi] = i3[qi] = 0;
  }

  const float* vgbase = value + (size_t)(n * LIN + l * HWsp) * DM + h * DH + d;

  for (int kc = 0; kc < 16; ++kc) {
    // Stage V^T chunk: vT[d][kk] = value row (kc*64+kk)
    {
      const float* vg = vgbase + (size_t)(kc << 6) * DM;
      #pragma unroll
      for (int i = 0; i < 8; ++i) vT[d][r + (i << 3)] = vg[(size_t)(r + (i << 3)) * DM];
    }
    __syncthreads();  // vT ready

    // 4x4 register tile: q = qb + 4*tq+qi, k = kc*64 + 4*tk+kj
    float a00 = 0.f, a01 = 0.f, a02 = 0.f, a03 = 0.f;
    float a10 = 0.f, a11 = 0.f, a12 = 0.f, a13 = 0.f;
    float a20 = 0.f, a21 = 0.f, a22 = 0.f, a23 = 0.f;
    float a30 = 0.f, a31 = 0.f, a32 = 0.f, a33 = 0.f;
    #pragma unroll
    for (int d0 = 0; d0 < 32; ++d0) {
      const float4 qv = *(const float4*)&qT[d0][tq << 2];
      const float4 vv = *(const float4*)&vT[d0][tk << 2];
      a00 = fmaf(qv.x, vv.x, a00); a01 = fmaf(qv.x, vv.y, a01);
      a02 = fmaf(qv.x, vv.z, a02); a03 = fmaf(qv.x, vv.w, a03);
      a10 = fmaf(qv.y, vv.x, a10); a11 = fmaf(qv.y, vv.y, a11);
      a12 = fmaf(qv.y, vv.z, a12); a13 = fmaf(qv.y, vv.w, a13);
      a20 = fmaf(qv.z, vv.x, a20); a21 = fmaf(qv.z, vv.y, a21);
      a22 = fmaf(qv.z, vv.z, a22); a23 = fmaf(qv.z, vv.w, a23);
      a30 = fmaf(qv.w, vv.x, a30); a31 = fmaf(qv.w, vv.y, a31);
      a32 = fmaf(qv.w, vv.z, a32); a33 = fmaf(qv.w, vv.w, a33);
    }

    // local stable top-4 update (ascending k within this thread's columns)
    {
      const int kb = (kc << 6) + (tk << 2);
      INSERT4Q(0, a00, kb + 0); INSERT4Q(0, a01, kb + 1);
      INSERT4Q(0, a02, kb + 2); INSERT4Q(0, a03, kb + 3);
      INSERT4Q(1, a10, kb + 0); INSERT4Q(1, a11, kb + 1);
      INSERT4Q(1, a12, kb + 2); INSERT4Q(1, a13, kb + 3);
      INSERT4Q(2, a20, kb + 0); INSERT4Q(2, a21, kb + 1);
      INSERT4Q(2, a22, kb + 2); INSERT4Q(2, a23, kb + 3);
      INSERT4Q(3, a30, kb + 0); INSERT4Q(3, a31, kb + 1);
      INSERT4Q(3, a32, kb + 2); INSERT4Q(3, a33, kb + 3);
    }
    __syncthreads();  // all reads of vT done before next stage
  }

  // Butterfly lexicographic merge across the 16 tk-threads (validated in R2)
  #pragma unroll
  for (int m = 1; m < 16; m <<= 1) {
    #pragma unroll
    for (int qi = 0; qi < 4; ++qi) {
      const float b0 = __shfl_xor(v0[qi], m);
      const float b1 = __shfl_xor(v1[qi], m);
      const float b2 = __shfl_xor(v2[qi], m);
      const float b3 = __shfl_xor(v3[qi], m);
      const int j0 = __shfl_xor(i0[qi], m);
      const int j1 = __shfl_xor(i1[qi], m);
      const int j2 = __shfl_xor(i2[qi], m);
      const int j3 = __shfl_xor(i3[qi], m);
      // L_i = lexmax(a_i, b_{3-i}) -> bitonic, contains union top-4
      LMAX(v0[qi], i0[qi], b3, j3);
      LMAX(v1[qi], i1[qi], b2, j2);
      LMAX(v2[qi], i2[qi], b1, j1);
      LMAX(v3[qi], i3[qi], b0, j0);
      // bitonic sort4 desc
      CEX(v0[qi], i0[qi], v2[qi], i2[qi]);
      CEX(v1[qi], i1[qi], v3[qi], i3[qi]);
      CEX(v0[qi], i0[qi], v1[qi], i1[qi]);
      CEX(v2[qi], i2[qi], v3[qi], i3[qi]);
    }
  }

  if (tk == 0) {
    #pragma unroll
    for (int qi = 0; qi < 4; ++qi) {
      const int q = qb + tq * 4 + qi;
      // idx_buf layout: [n][h][l][q][4] int32
      ((int4*)idx_out)[(((size_t)nh * NL + l) << 10) + q] =
          make_int4(i0[qi], i1[qi], i2[qi], i3[qi]);
    }
  }
}

// ---------------------------------------------------------------------------
// Kernel 2: loc output. res=clip(idx+delta,0,961); loc=(res>>5, res&31)/32.
// One thread per (n,q,h,l,k9) pair -> writes float2. Exact in fp32.
// ---------------------------------------------------------------------------
__global__ __launch_bounds__(256) void loc_kernel(const int* __restrict__ idx_buf,
                                                  float* __restrict__ loc) {
  const int t = blockIdx.x * 256 + threadIdx.x;  // < 2359296
  const int k = t % 36;
  int rest = t / 36;
  const int l = rest & 3; rest >>= 2;
  const int h = rest & 7; rest >>= 3;
  const int q = rest & 1023;
  const int n = rest >> 10;
  const int p = k & 3, dd = k >> 2;  // delta-major: k = dd*4 + p
  const int idx = idx_buf[(((((n << 3) + h) * NL + l) << 10) + q) * 4 + p];
  const int delta = ((dd / 3) - 1) * 32 + (dd % 3) - 1;  // {-33,-32,-31,-1,0,1,31,32,33}
  int res = idx + delta;
  res = min(max(res, 0), 961);
  const int W = res >> 5, H = res & 31;
  ((float2*)loc)[t] = make_float2((float)W * 0.03125f, (float)H * 0.03125f);
}

// ---------------------------------------------------------------------------
// Kernel 3: gather+average. All bilinear weights are exactly 0.25; corners of
// cell (H=res&31, W=res>>5) are rows {g, g-1, g-32, g-33}, g = H*32+W, gated
// by W>=1 / H>=1 (gates applied as 0/1 weights, addresses clamped to >=0 so
// loads are unconditional and exec-full -> no divergence).
// Block = (n,q); thread = (l, h, d4): wave = one level; float4 per lane ->
// 1 KiB per load instruction; 144 independent loads per thread.
// LDS reduction over the 4 levels at the end. acc = (1/576) * sum.
// ---------------------------------------------------------------------------
__global__ __launch_bounds__(256) void gather_kernel(
    const float* __restrict__ value, const int* __restrict__ idx_buf,
    float* __restrict__ acc_out) {
  __shared__ float red[NL][DM];
  const int nq = blockIdx.x;  // n*1024+q
  const int n = nq >> 10, q = nq & 1023;
  const int tid = threadIdx.x;
  const int l = tid >> 6;          // wave index = level
  const int h = (tid >> 3) & 7;
  const int d4 = tid & 7;          // float4 lane within the 32-float head dim

  const int4 id4 =
      ((const int4*)idx_buf)[((((size_t)((n << 3) + h)) * NL + l) << 10) + q];

  // base: value[n][l*1024 + row][h*32 + d4*4 ..], row stride = 64 float4
  const float4* vb4 =
      (const float4*)(value + (size_t)(n * LIN + l * HWsp) * DM + h * DH) + d4;

  float4 a = make_float4(0.f, 0.f, 0.f, 0.f);
  #pragma unroll
  for (int p = 0; p < 4; ++p) {
    const int idx = (p == 0) ? id4.x : (p == 1) ? id4.y : (p == 2) ? id4.z : id4.w;
    #pragma unroll
    for (int dy = -1; dy <= 1; ++dy) {
      #pragma unroll
      for (int dx = -1; dx <= 1; ++dx) {
        int res = idx + dy * 32 + dx;
        res = min(max(res, 0), 961);
        const int W = res >> 5, H = res & 31;
        const int g = (H << 5) + W;
        const float wW = (W >= 1) ? 1.f : 0.f;
        const float wH = (H >= 1) ? 1.f : 0.f;
        const float wB = wW * wH;
        const float4 c0 = vb4[(size_t)g * 64];
        const float4 c1 = vb4[(size_t)max(g - 1, 0) * 64];
        const float4 c2 = vb4[(size_t)max(g - 32, 0) * 64];
        const float4 c3 = vb4[(size_t)max(g - 33, 0) * 64];
        a.x += c0.x + wW * c1.x + wH * c2.x + wB * c3.x;
        a.y += c0.y + wW * c1.y + wH * c2.y + wB * c3.y;
        a.z += c0.z + wW * c1.z + wH * c2.z + wB * c3.z;
        a.w += c0.w + wW * c1.w + wH * c2.w + wB * c3.w;
      }
    }
  }

  const int col = h * DH + d4 * 4;
  red[l][col + 0] = a.x;
  red[l][col + 1] = a.y;
  red[l][col + 2] = a.z;
  red[l][col + 3] = a.w;
  __syncthreads();
  const float s = red[0][tid] + red[1][tid] + red[2][tid] + red[3][tid];
  acc_out[(size_t)nq * DM + tid] = s * (1.0f / 576.0f);
}

// ---------------------------------------------------------------------------
// Kernel 4: out = acc @ W^T + b.  256 blocks x 256 threads, 8 q-rows/block.
// ---------------------------------------------------------------------------
__global__ __launch_bounds__(256) void proj_kernel(
    const float* __restrict__ acc_in, const float* __restrict__ W,
    const float* __restrict__ bias, float* __restrict__ out) {
  __shared__ float la[8][256];
  const int qb = blockIdx.x << 3;
  const int tid = threadIdx.x;
  for (int i = tid; i < 8 * 256; i += 256)
    la[i >> 8][i & 255] = acc_in[((size_t)qb << 8) + i];
  __syncthreads();
  const float* wrow = W + (size_t)tid * 256;
  float s0 = 0.f, s1 = 0.f, s2 = 0.f, s3 = 0.f, s4 = 0.f, s5 = 0.f, s6 = 0.f, s7 = 0.f;
  for (int c0 = 0; c0 < 256; c0 += 4) {
    const float4 wv = *(const float4*)(wrow + c0);
    #define PROJ_STEP(qi, sreg)                                   \
      {                                                           \
        const float4 av = *(const float4*)&la[qi][c0];            \
        sreg = fmaf(wv.x, av.x, sreg);                            \
        sreg = fmaf(wv.y, av.y, sreg);                            \
        sreg = fmaf(wv.z, av.z, sreg);                            \
        sreg = fmaf(wv.w, av.w, sreg);                            \
      }
    PROJ_STEP(0, s0) PROJ_STEP(1, s1) PROJ_STEP(2, s2) PROJ_STEP(3, s3)
    PROJ_STEP(4, s4) PROJ_STEP(5, s5) PROJ_STEP(6, s6) PROJ_STEP(7, s7)
    #undef PROJ_STEP
  }
  const float bj = bias[tid];
  out[(size_t)(qb + 0) * 256 + tid] = s0 + bj;
  out[(size_t)(qb + 1) * 256 + tid] = s1 + bj;
  out[(size_t)(qb + 2) * 256 + tid] = s2 + bj;
  out[(size_t)(qb + 3) * 256 + tid] = s3 + bj;
  out[(size_t)(qb + 4) * 256 + tid] = s4 + bj;
  out[(size_t)(qb + 5) * 256 + tid] = s5 + bj;
  out[(size_t)(qb + 6) * 256 + tid] = s6 + bj;
  out[(size_t)(qb + 7) * 256 + tid] = s7 + bj;
}

// ---------------------------------------------------------------------------
extern "C" void kernel_launch(void* const* d_in, const int* in_sizes, int n_in,
                              void* d_out, int out_size, void* d_ws, size_t ws_size,
                              hipStream_t stream) {
  (void)in_sizes; (void)n_in; (void)out_size; (void)ws_size;
  const float* query = (const float*)d_in[0];
  // d_in[1] reference_points: unused by the reference math
  const float* value = (const float*)d_in[2];
  // d_in[3], d_in[4]: spatial shapes / level start (int64) -- constants here
  const float* opw = (const float*)d_in[5];
  const float* opb = (const float*)d_in[6];

  float* out = (float*)d_out;                       // [2,1024,256]
  float* loc = out + (size_t)BB * LQ * DM;          // [2,1024,8,4,36,2]

  int* idx_buf = (int*)d_ws;                                        // 1 MB
  float* acc_buf = (float*)((char*)d_ws + (size_t)BB * NH * NL * LQ * 4 * sizeof(int));

  corr_topk_kernel<<<dim3(16, NL, BB * NH), 256, 0, stream>>>(query, value, idx_buf);
  loc_kernel<<<dim3((BB * LQ * NH * NL * K9) / 256), 256, 0, stream>>>(idx_buf, loc);
  gather_kernel<<<dim3(BB * LQ), 256, 0, stream>>>(value, idx_buf, acc_buf);
  proj_kernel<<<dim3(BB * LQ / 8), 256, 0, stream>>>(acc_buf, opw, opb, out);
}